// Round 1
// baseline (1699.891 us; speedup 1.0000x reference)
//
#include <hip/hip_runtime.h>

#define M_NODES 100000
#define K_FEAT 512
#define N_OUT_C 64
#define N_EDGES_C 1600000

// ---------------------------------------------------------------------------
// Kernel 1: h[M,64] = x[M,512] @ W[512,64]   (fp32 SIMT tiled GEMM)
// Tile: BM=64, BN=64(=N), BK=32. Block 256 threads, each computes 4x4 outputs.
// ---------------------------------------------------------------------------
__global__ __launch_bounds__(256) void gemm_xw(const float* __restrict__ x,
                                               const float* __restrict__ W,
                                               float* __restrict__ h) {
    __shared__ float As[64][33];   // [BM][BK+1] pad to break bank conflicts
    __shared__ float Bs[32][64];   // [BK][BN]

    const int t  = threadIdx.x;
    const int tx = t & 15;         // 16 cols of threads -> 4 outs each (n)
    const int ty = t >> 4;         // 16 rows of threads -> 4 outs each (m)
    const int rowBase = blockIdx.x * 64;

    float acc[4][4] = {{0.f}};

    for (int k0 = 0; k0 < K_FEAT; k0 += 32) {
        // --- stage x tile: 64 rows x 32 cols = 512 float4, 2 per thread ---
        #pragma unroll
        for (int i = 0; i < 2; i++) {
            int f   = t + i * 256;       // float4 index in tile
            int r   = f >> 3;            // row within tile (8 float4 per row)
            int c4  = f & 7;             // float4 col
            int grow = rowBase + r;
            float4 v = make_float4(0.f, 0.f, 0.f, 0.f);
            if (grow < M_NODES)
                v = *(const float4*)&x[(size_t)grow * K_FEAT + k0 + c4 * 4];
            As[r][c4 * 4 + 0] = v.x;
            As[r][c4 * 4 + 1] = v.y;
            As[r][c4 * 4 + 2] = v.z;
            As[r][c4 * 4 + 3] = v.w;
        }
        // --- stage W tile: rows k0..k0+31 x 64 cols = contiguous 2048 floats ---
        #pragma unroll
        for (int i = 0; i < 2; i++) {
            int f = t + i * 256;
            ((float4*)Bs)[f] = ((const float4*)(W + (size_t)k0 * N_OUT_C))[f];
        }
        __syncthreads();

        #pragma unroll
        for (int k = 0; k < 32; k++) {
            float a0 = As[ty * 4 + 0][k];
            float a1 = As[ty * 4 + 1][k];
            float a2 = As[ty * 4 + 2][k];
            float a3 = As[ty * 4 + 3][k];
            float4 b = *(float4*)&Bs[k][tx * 4];
            acc[0][0] += a0 * b.x; acc[0][1] += a0 * b.y; acc[0][2] += a0 * b.z; acc[0][3] += a0 * b.w;
            acc[1][0] += a1 * b.x; acc[1][1] += a1 * b.y; acc[1][2] += a1 * b.z; acc[1][3] += a1 * b.w;
            acc[2][0] += a2 * b.x; acc[2][1] += a2 * b.y; acc[2][2] += a2 * b.z; acc[2][3] += a2 * b.w;
            acc[3][0] += a3 * b.x; acc[3][1] += a3 * b.y; acc[3][2] += a3 * b.z; acc[3][3] += a3 * b.w;
        }
        __syncthreads();
    }

    #pragma unroll
    for (int i = 0; i < 4; i++) {
        int row = rowBase + ty * 4 + i;
        if (row < M_NODES) {
            float4 v = make_float4(acc[i][0], acc[i][1], acc[i][2], acc[i][3]);
            *(float4*)&h[(size_t)row * N_OUT_C + tx * 4] = v;
        }
    }
}

// ---------------------------------------------------------------------------
// Kernel 2: for each edge e: agg[dst[e]] += w[e] * h[src[e]]
// 16 threads per edge, 4 channels each (float4 gather + 4 HW fp32 atomics).
// ---------------------------------------------------------------------------
__global__ __launch_bounds__(256) void scatter_edges(const int* __restrict__ esrc,
                                                     const int* __restrict__ edst,
                                                     const float* __restrict__ ew,
                                                     const float* __restrict__ h,
                                                     float* __restrict__ agg) {
    int tid = blockIdx.x * 256 + threadIdx.x;
    int e = tid >> 4;
    int g = tid & 15;
    if (e >= N_EDGES_C) return;

    int s   = esrc[e];
    int d   = edst[e];
    float w = ew[e];

    float4 v = *(const float4*)&h[(size_t)s * N_OUT_C + g * 4];
    float* p = agg + (size_t)d * N_OUT_C + g * 4;
    unsafeAtomicAdd(p + 0, v.x * w);
    unsafeAtomicAdd(p + 1, v.y * w);
    unsafeAtomicAdd(p + 2, v.z * w);
    unsafeAtomicAdd(p + 3, v.w * w);
}

// ---------------------------------------------------------------------------
// Kernel 3: row softmax in place. One wave (64 lanes) per node, 64 channels.
// ---------------------------------------------------------------------------
__global__ __launch_bounds__(256) void softmax_rows(float* __restrict__ out) {
    int wave = (blockIdx.x * 256 + threadIdx.x) >> 6;
    int lane = threadIdx.x & 63;
    if (wave >= M_NODES) return;

    size_t idx = (size_t)wave * N_OUT_C + lane;
    float v = out[idx];

    float m = v;
    #pragma unroll
    for (int off = 32; off > 0; off >>= 1)
        m = fmaxf(m, __shfl_xor(m, off));

    float ev = __expf(v - m);

    float sum = ev;
    #pragma unroll
    for (int off = 32; off > 0; off >>= 1)
        sum += __shfl_xor(sum, off);

    out[idx] = ev / sum;
}

// ---------------------------------------------------------------------------
extern "C" void kernel_launch(void* const* d_in, const int* in_sizes, int n_in,
                              void* d_out, int out_size, void* d_ws, size_t ws_size,
                              hipStream_t stream) {
    const float* x    = (const float*)d_in[0];
    const int*   esrc = (const int*)d_in[1];
    const int*   edst = (const int*)d_in[2];
    const float* ew   = (const float*)d_in[3];
    const float* W    = (const float*)d_in[4];
    float* out = (float*)d_out;
    float* h   = (float*)d_ws;   // 100000*64 fp32 = 25.6 MB scratch

    // agg accumulates directly in d_out; it is poisoned each call -> zero it.
    hipMemsetAsync(d_out, 0, (size_t)M_NODES * N_OUT_C * sizeof(float), stream);

    gemm_xw<<<(M_NODES + 63) / 64, 256, 0, stream>>>(x, W, h);

    scatter_edges<<<(N_EDGES_C * 16 + 255) / 256, 256, 0, stream>>>(esrc, edst, ew, h, out);

    softmax_rows<<<(M_NODES + 3) / 4, 256, 0, stream>>>(out);
}

// Round 2
// 798.675 us; speedup vs baseline: 2.1284x; 2.1284x over previous
//
#include <hip/hip_runtime.h>

#define M_NODES 100000
#define K_FEAT 512
#define N_OUT_C 64
#define N_EDGES_C 1600000

// ---------------------------------------------------------------------------
// Kernel 1: h[M,64] = x[M,512] @ W[512,64]   (fp32 SIMT tiled GEMM)
// ---------------------------------------------------------------------------
__global__ __launch_bounds__(256) void gemm_xw(const float* __restrict__ x,
                                               const float* __restrict__ W,
                                               float* __restrict__ h) {
    __shared__ float As[64][33];
    __shared__ float Bs[32][64];

    const int t  = threadIdx.x;
    const int tx = t & 15;
    const int ty = t >> 4;
    const int rowBase = blockIdx.x * 64;

    float acc[4][4] = {{0.f}};

    for (int k0 = 0; k0 < K_FEAT; k0 += 32) {
        #pragma unroll
        for (int i = 0; i < 2; i++) {
            int f   = t + i * 256;
            int r   = f >> 3;
            int c4  = f & 7;
            int grow = rowBase + r;
            float4 v = make_float4(0.f, 0.f, 0.f, 0.f);
            if (grow < M_NODES)
                v = *(const float4*)&x[(size_t)grow * K_FEAT + k0 + c4 * 4];
            As[r][c4 * 4 + 0] = v.x;
            As[r][c4 * 4 + 1] = v.y;
            As[r][c4 * 4 + 2] = v.z;
            As[r][c4 * 4 + 3] = v.w;
        }
        #pragma unroll
        for (int i = 0; i < 2; i++) {
            int f = t + i * 256;
            ((float4*)Bs)[f] = ((const float4*)(W + (size_t)k0 * N_OUT_C))[f];
        }
        __syncthreads();

        #pragma unroll
        for (int k = 0; k < 32; k++) {
            float a0 = As[ty * 4 + 0][k];
            float a1 = As[ty * 4 + 1][k];
            float a2 = As[ty * 4 + 2][k];
            float a3 = As[ty * 4 + 3][k];
            float4 b = *(float4*)&Bs[k][tx * 4];
            acc[0][0] += a0 * b.x; acc[0][1] += a0 * b.y; acc[0][2] += a0 * b.z; acc[0][3] += a0 * b.w;
            acc[1][0] += a1 * b.x; acc[1][1] += a1 * b.y; acc[1][2] += a1 * b.z; acc[1][3] += a1 * b.w;
            acc[2][0] += a2 * b.x; acc[2][1] += a2 * b.y; acc[2][2] += a2 * b.z; acc[2][3] += a2 * b.w;
            acc[3][0] += a3 * b.x; acc[3][1] += a3 * b.y; acc[3][2] += a3 * b.z; acc[3][3] += a3 * b.w;
        }
        __syncthreads();
    }

    #pragma unroll
    for (int i = 0; i < 4; i++) {
        int row = rowBase + ty * 4 + i;
        if (row < M_NODES) {
            float4 v = make_float4(acc[i][0], acc[i][1], acc[i][2], acc[i][3]);
            *(float4*)&h[(size_t)row * N_OUT_C + tx * 4] = v;
        }
    }
}

// ---------------------------------------------------------------------------
// CSR build: histogram of edge destinations
// ---------------------------------------------------------------------------
__global__ __launch_bounds__(256) void hist_dst(const int* __restrict__ edst,
                                                int* __restrict__ deg) {
    int e = blockIdx.x * 256 + threadIdx.x;
    if (e < N_EDGES_C) atomicAdd(&deg[edst[e]], 1);
}

// ---------------------------------------------------------------------------
// Single-block exclusive scan over deg[0..N) -> offsets[0..N], cursor[0..N)
// 1024 threads, each handles a contiguous chunk; Hillis-Steele on chunk sums.
// ---------------------------------------------------------------------------
__global__ __launch_bounds__(1024) void scan_deg(const int* __restrict__ deg,
                                                 int* __restrict__ offsets,
                                                 int* __restrict__ cursor) {
    __shared__ int sums[1024];
    const int t = threadIdx.x;
    const int CH = (M_NODES + 1023) / 1024;   // 98
    int lo = t * CH;
    int hi = min(lo + CH, M_NODES);

    int mySum = 0;
    for (int i = lo; i < hi; i++) mySum += deg[i];
    sums[t] = mySum;
    __syncthreads();

    for (int off = 1; off < 1024; off <<= 1) {
        int v = (t >= off) ? sums[t - off] : 0;
        __syncthreads();
        sums[t] += v;
        __syncthreads();
    }
    int running = sums[t] - mySum;   // exclusive prefix of this chunk

    for (int i = lo; i < hi; i++) {
        offsets[i] = running;
        cursor[i]  = running;
        running += deg[i];
    }
    if (t == 1023) offsets[M_NODES] = sums[1023];
}

// ---------------------------------------------------------------------------
// Fill CSR: for each edge write (src, w) into its destination's segment.
// ---------------------------------------------------------------------------
__global__ __launch_bounds__(256) void fill_csr(const int* __restrict__ esrc,
                                                const int* __restrict__ edst,
                                                const float* __restrict__ ew,
                                                int* __restrict__ cursor,
                                                int2* __restrict__ csr) {
    int e = blockIdx.x * 256 + threadIdx.x;
    if (e >= N_EDGES_C) return;
    int d = edst[e];
    int pos = atomicAdd(&cursor[d], 1);
    csr[pos] = make_int2(esrc[e], __float_as_int(ew[e]));
}

// ---------------------------------------------------------------------------
// Gather + softmax fused: one wave per node, lane = channel.
// ---------------------------------------------------------------------------
__global__ __launch_bounds__(256) void gather_softmax(const int* __restrict__ offsets,
                                                      const int2* __restrict__ csr,
                                                      const float* __restrict__ h,
                                                      float* __restrict__ out) {
    int node = (blockIdx.x * 256 + threadIdx.x) >> 6;
    int lane = threadIdx.x & 63;
    if (node >= M_NODES) return;

    int start = offsets[node];
    int end   = offsets[node + 1];

    float acc = 0.f;
    for (int base = start; base < end; base += 64) {
        int n = min(64, end - base);
        int2 q = make_int2(0, 0);
        if (lane < n) q = csr[base + lane];

        int j = 0;
        for (; j + 4 <= n; j += 4) {
            int   s0 = __shfl(q.x, j + 0); float w0 = __shfl(__int_as_float(q.y), j + 0);
            int   s1 = __shfl(q.x, j + 1); float w1 = __shfl(__int_as_float(q.y), j + 1);
            int   s2 = __shfl(q.x, j + 2); float w2 = __shfl(__int_as_float(q.y), j + 2);
            int   s3 = __shfl(q.x, j + 3); float w3 = __shfl(__int_as_float(q.y), j + 3);
            float v0 = h[(size_t)s0 * N_OUT_C + lane];
            float v1 = h[(size_t)s1 * N_OUT_C + lane];
            float v2 = h[(size_t)s2 * N_OUT_C + lane];
            float v3 = h[(size_t)s3 * N_OUT_C + lane];
            acc += w0 * v0 + w1 * v1 + w2 * v2 + w3 * v3;
        }
        for (; j < n; j++) {
            int   s = __shfl(q.x, j);
            float w = __shfl(__int_as_float(q.y), j);
            acc += w * h[(size_t)s * N_OUT_C + lane];
        }
    }

    // softmax across the wave (64 channels)
    float m = acc;
    #pragma unroll
    for (int off = 32; off > 0; off >>= 1)
        m = fmaxf(m, __shfl_xor(m, off));
    float ev = __expf(acc - m);
    float sum = ev;
    #pragma unroll
    for (int off = 32; off > 0; off >>= 1)
        sum += __shfl_xor(sum, off);

    out[(size_t)node * N_OUT_C + lane] = ev / sum;
}

// ---------------------------------------------------------------------------
// Fallback path kernels (R1): atomic scatter + standalone softmax
// ---------------------------------------------------------------------------
__global__ __launch_bounds__(256) void scatter_edges(const int* __restrict__ esrc,
                                                     const int* __restrict__ edst,
                                                     const float* __restrict__ ew,
                                                     const float* __restrict__ h,
                                                     float* __restrict__ agg) {
    int tid = blockIdx.x * 256 + threadIdx.x;
    int e = tid >> 4;
    int g = tid & 15;
    if (e >= N_EDGES_C) return;
    int s   = esrc[e];
    int d   = edst[e];
    float w = ew[e];
    float4 v = *(const float4*)&h[(size_t)s * N_OUT_C + g * 4];
    float* p = agg + (size_t)d * N_OUT_C + g * 4;
    unsafeAtomicAdd(p + 0, v.x * w);
    unsafeAtomicAdd(p + 1, v.y * w);
    unsafeAtomicAdd(p + 2, v.z * w);
    unsafeAtomicAdd(p + 3, v.w * w);
}

__global__ __launch_bounds__(256) void softmax_rows(float* __restrict__ out) {
    int wave = (blockIdx.x * 256 + threadIdx.x) >> 6;
    int lane = threadIdx.x & 63;
    if (wave >= M_NODES) return;
    size_t idx = (size_t)wave * N_OUT_C + lane;
    float v = out[idx];
    float m = v;
    #pragma unroll
    for (int off = 32; off > 0; off >>= 1)
        m = fmaxf(m, __shfl_xor(m, off));
    float ev = __expf(v - m);
    float sum = ev;
    #pragma unroll
    for (int off = 32; off > 0; off >>= 1)
        sum += __shfl_xor(sum, off);
    out[idx] = ev / sum;
}

// ---------------------------------------------------------------------------
extern "C" void kernel_launch(void* const* d_in, const int* in_sizes, int n_in,
                              void* d_out, int out_size, void* d_ws, size_t ws_size,
                              hipStream_t stream) {
    const float* x    = (const float*)d_in[0];
    const int*   esrc = (const int*)d_in[1];
    const int*   edst = (const int*)d_in[2];
    const float* ew   = (const float*)d_in[3];
    const float* W    = (const float*)d_in[4];
    float* out = (float*)d_out;

    // workspace layout (16B-aligned chunks)
    char* ws = (char*)d_ws;
    size_t off_h      = 0;
    size_t sz_h       = (size_t)M_NODES * N_OUT_C * sizeof(float);      // 25.6 MB
    size_t off_deg    = (off_h + sz_h + 15) & ~15ull;
    size_t sz_deg     = (size_t)M_NODES * sizeof(int);                  // 400 KB
    size_t off_offs   = (off_deg + sz_deg + 15) & ~15ull;
    size_t sz_offs    = (size_t)(M_NODES + 1) * sizeof(int);
    size_t off_cur    = (off_offs + sz_offs + 15) & ~15ull;
    size_t sz_cur     = (size_t)M_NODES * sizeof(int);
    size_t off_csr    = (off_cur + sz_cur + 15) & ~15ull;
    size_t sz_csr     = (size_t)N_EDGES_C * sizeof(int2);               // 12.8 MB
    size_t needed     = off_csr + sz_csr;

    float* h = (float*)(ws + off_h);

    gemm_xw<<<(M_NODES + 63) / 64, 256, 0, stream>>>(x, W, h);

    if (ws_size >= needed) {
        int*  deg     = (int*)(ws + off_deg);
        int*  offsets = (int*)(ws + off_offs);
        int*  cursor  = (int*)(ws + off_cur);
        int2* csr     = (int2*)(ws + off_csr);

        hipMemsetAsync(deg, 0, sz_deg, stream);
        hist_dst<<<(N_EDGES_C + 255) / 256, 256, 0, stream>>>(edst, deg);
        scan_deg<<<1, 1024, 0, stream>>>(deg, offsets, cursor);
        fill_csr<<<(N_EDGES_C + 255) / 256, 256, 0, stream>>>(esrc, edst, ew, cursor, csr);
        gather_softmax<<<(M_NODES * 64 + 255) / 256, 256, 0, stream>>>(offsets, csr, h, out);
    } else {
        // fallback: atomic scatter (R1 path)
        hipMemsetAsync(d_out, 0, (size_t)M_NODES * N_OUT_C * sizeof(float), stream);
        scatter_edges<<<(N_EDGES_C * 16 + 255) / 256, 256, 0, stream>>>(esrc, edst, ew, h, out);
        softmax_rows<<<(M_NODES + 3) / 4, 256, 0, stream>>>(out);
    }
}

// Round 3
// 583.688 us; speedup vs baseline: 2.9123x; 1.3683x over previous
//
#include <hip/hip_runtime.h>

#define M_NODES 100000
#define K_FEAT 512
#define N_OUT_C 64
#define N_EDGES_C 1600000

#define SCAN_CHUNK 1024
#define SCAN_BLOCKS ((M_NODES + SCAN_CHUNK - 1) / SCAN_CHUNK)   // 98

// ---------------------------------------------------------------------------
// Kernel 1: h[M,64] = x[M,512] @ W[512,64]   (fp32 SIMT tiled GEMM)
// ---------------------------------------------------------------------------
__global__ __launch_bounds__(256) void gemm_xw(const float* __restrict__ x,
                                               const float* __restrict__ W,
                                               float* __restrict__ h) {
    __shared__ float As[64][33];
    __shared__ float Bs[32][64];

    const int t  = threadIdx.x;
    const int tx = t & 15;
    const int ty = t >> 4;
    const int rowBase = blockIdx.x * 64;

    float acc[4][4] = {{0.f}};

    for (int k0 = 0; k0 < K_FEAT; k0 += 32) {
        #pragma unroll
        for (int i = 0; i < 2; i++) {
            int f   = t + i * 256;
            int r   = f >> 3;
            int c4  = f & 7;
            int grow = rowBase + r;
            float4 v = make_float4(0.f, 0.f, 0.f, 0.f);
            if (grow < M_NODES)
                v = *(const float4*)&x[(size_t)grow * K_FEAT + k0 + c4 * 4];
            As[r][c4 * 4 + 0] = v.x;
            As[r][c4 * 4 + 1] = v.y;
            As[r][c4 * 4 + 2] = v.z;
            As[r][c4 * 4 + 3] = v.w;
        }
        #pragma unroll
        for (int i = 0; i < 2; i++) {
            int f = t + i * 256;
            ((float4*)Bs)[f] = ((const float4*)(W + (size_t)k0 * N_OUT_C))[f];
        }
        __syncthreads();

        #pragma unroll
        for (int k = 0; k < 32; k++) {
            float a0 = As[ty * 4 + 0][k];
            float a1 = As[ty * 4 + 1][k];
            float a2 = As[ty * 4 + 2][k];
            float a3 = As[ty * 4 + 3][k];
            float4 b = *(float4*)&Bs[k][tx * 4];
            acc[0][0] += a0 * b.x; acc[0][1] += a0 * b.y; acc[0][2] += a0 * b.z; acc[0][3] += a0 * b.w;
            acc[1][0] += a1 * b.x; acc[1][1] += a1 * b.y; acc[1][2] += a1 * b.z; acc[1][3] += a1 * b.w;
            acc[2][0] += a2 * b.x; acc[2][1] += a2 * b.y; acc[2][2] += a2 * b.z; acc[2][3] += a2 * b.w;
            acc[3][0] += a3 * b.x; acc[3][1] += a3 * b.y; acc[3][2] += a3 * b.z; acc[3][3] += a3 * b.w;
        }
        __syncthreads();
    }

    #pragma unroll
    for (int i = 0; i < 4; i++) {
        int row = rowBase + ty * 4 + i;
        if (row < M_NODES) {
            float4 v = make_float4(acc[i][0], acc[i][1], acc[i][2], acc[i][3]);
            *(float4*)&h[(size_t)row * N_OUT_C + tx * 4] = v;
        }
    }
}

// ---------------------------------------------------------------------------
// CSR build: histogram of edge destinations
// ---------------------------------------------------------------------------
__global__ __launch_bounds__(256) void hist_dst(const int* __restrict__ edst,
                                                int* __restrict__ deg) {
    int e = blockIdx.x * 256 + threadIdx.x;
    if (e < N_EDGES_C) atomicAdd(&deg[edst[e]], 1);
}

// ---------------------------------------------------------------------------
// Multi-block exclusive scan of deg[0..M) -> offsets[0..M], cursor[0..M)
// pass1: per-block sums; pass2: scan of 98 block sums; pass3: emit prefixes.
// Each block covers SCAN_CHUNK=1024 elements (256 threads x int4).
// M_NODES % 4 == 0 and bases are 4-aligned, so int4 guards are whole-vector.
// ---------------------------------------------------------------------------
__global__ __launch_bounds__(256) void scan_pass1(const int* __restrict__ deg,
                                                  int* __restrict__ bsums) {
    __shared__ int red[4];
    int base = blockIdx.x * SCAN_CHUNK + threadIdx.x * 4;
    int s = 0;
    if (base < M_NODES) {
        int4 v = *(const int4*)&deg[base];
        s = v.x + v.y + v.z + v.w;
    }
    // wave reduce
    #pragma unroll
    for (int off = 32; off > 0; off >>= 1) s += __shfl_xor(s, off);
    int wv = threadIdx.x >> 6;
    if ((threadIdx.x & 63) == 0) red[wv] = s;
    __syncthreads();
    if (threadIdx.x == 0)
        bsums[blockIdx.x] = red[0] + red[1] + red[2] + red[3];
}

__global__ __launch_bounds__(128) void scan_pass2(const int* __restrict__ bsums,
                                                  int* __restrict__ boffs,
                                                  int* __restrict__ offsets) {
    __shared__ int sh[128];
    int t = threadIdx.x;
    int v = (t < SCAN_BLOCKS) ? bsums[t] : 0;
    sh[t] = v;
    __syncthreads();
    #pragma unroll
    for (int off = 1; off < 128; off <<= 1) {
        int u = (t >= off) ? sh[t - off] : 0;
        __syncthreads();
        sh[t] += u;
        __syncthreads();
    }
    if (t < SCAN_BLOCKS) boffs[t] = sh[t] - v;          // exclusive
    if (t == 127) offsets[M_NODES] = sh[127];           // total = N_EDGES
}

__global__ __launch_bounds__(256) void scan_pass3(const int* __restrict__ deg,
                                                  const int* __restrict__ boffs,
                                                  int* __restrict__ offsets,
                                                  int* __restrict__ cursor) {
    __shared__ int sh[256];
    int t = threadIdx.x;
    int base = blockIdx.x * SCAN_CHUNK + t * 4;

    int4 v = make_int4(0, 0, 0, 0);
    if (base < M_NODES) v = *(const int4*)&deg[base];
    int s = v.x + v.y + v.z + v.w;

    sh[t] = s;
    __syncthreads();
    #pragma unroll
    for (int off = 1; off < 256; off <<= 1) {
        int u = (t >= off) ? sh[t - off] : 0;
        __syncthreads();
        sh[t] += u;
        __syncthreads();
    }
    int prefix = boffs[blockIdx.x] + sh[t] - s;   // exclusive prefix of this thread's 4

    if (base < M_NODES) {
        int4 o;
        o.x = prefix;
        o.y = o.x + v.x;
        o.z = o.y + v.y;
        o.w = o.z + v.z;
        *(int4*)&offsets[base] = o;
        *(int4*)&cursor[base]  = o;
    }
}

// ---------------------------------------------------------------------------
// Fill CSR: for each edge write (src, w) into its destination's segment.
// ---------------------------------------------------------------------------
__global__ __launch_bounds__(256) void fill_csr(const int* __restrict__ esrc,
                                                const int* __restrict__ edst,
                                                const float* __restrict__ ew,
                                                int* __restrict__ cursor,
                                                int2* __restrict__ csr) {
    int e = blockIdx.x * 256 + threadIdx.x;
    if (e >= N_EDGES_C) return;
    int d = edst[e];
    int pos = atomicAdd(&cursor[d], 1);
    csr[pos] = make_int2(esrc[e], __float_as_int(ew[e]));
}

// ---------------------------------------------------------------------------
// Gather + softmax fused: one wave per node, lane = channel.
// ---------------------------------------------------------------------------
__global__ __launch_bounds__(256) void gather_softmax(const int* __restrict__ offsets,
                                                      const int2* __restrict__ csr,
                                                      const float* __restrict__ h,
                                                      float* __restrict__ out) {
    int node = (blockIdx.x * 256 + threadIdx.x) >> 6;
    int lane = threadIdx.x & 63;
    if (node >= M_NODES) return;

    int start = offsets[node];
    int end   = offsets[node + 1];

    float acc = 0.f;
    for (int base = start; base < end; base += 64) {
        int n = min(64, end - base);
        int2 q = make_int2(0, 0);
        if (lane < n) q = csr[base + lane];

        int j = 0;
        for (; j + 4 <= n; j += 4) {
            int   s0 = __shfl(q.x, j + 0); float w0 = __shfl(__int_as_float(q.y), j + 0);
            int   s1 = __shfl(q.x, j + 1); float w1 = __shfl(__int_as_float(q.y), j + 1);
            int   s2 = __shfl(q.x, j + 2); float w2 = __shfl(__int_as_float(q.y), j + 2);
            int   s3 = __shfl(q.x, j + 3); float w3 = __shfl(__int_as_float(q.y), j + 3);
            float v0 = h[(size_t)s0 * N_OUT_C + lane];
            float v1 = h[(size_t)s1 * N_OUT_C + lane];
            float v2 = h[(size_t)s2 * N_OUT_C + lane];
            float v3 = h[(size_t)s3 * N_OUT_C + lane];
            acc += w0 * v0 + w1 * v1 + w2 * v2 + w3 * v3;
        }
        for (; j < n; j++) {
            int   s = __shfl(q.x, j);
            float w = __shfl(__int_as_float(q.y), j);
            acc += w * h[(size_t)s * N_OUT_C + lane];
        }
    }

    float m = acc;
    #pragma unroll
    for (int off = 32; off > 0; off >>= 1)
        m = fmaxf(m, __shfl_xor(m, off));
    float ev = __expf(acc - m);
    float sum = ev;
    #pragma unroll
    for (int off = 32; off > 0; off >>= 1)
        sum += __shfl_xor(sum, off);

    out[(size_t)node * N_OUT_C + lane] = ev / sum;
}

// ---------------------------------------------------------------------------
// Fallback path kernels (R1): atomic scatter + standalone softmax
// ---------------------------------------------------------------------------
__global__ __launch_bounds__(256) void scatter_edges(const int* __restrict__ esrc,
                                                     const int* __restrict__ edst,
                                                     const float* __restrict__ ew,
                                                     const float* __restrict__ h,
                                                     float* __restrict__ agg) {
    int tid = blockIdx.x * 256 + threadIdx.x;
    int e = tid >> 4;
    int g = tid & 15;
    if (e >= N_EDGES_C) return;
    int s   = esrc[e];
    int d   = edst[e];
    float w = ew[e];
    float4 v = *(const float4*)&h[(size_t)s * N_OUT_C + g * 4];
    float* p = agg + (size_t)d * N_OUT_C + g * 4;
    unsafeAtomicAdd(p + 0, v.x * w);
    unsafeAtomicAdd(p + 1, v.y * w);
    unsafeAtomicAdd(p + 2, v.z * w);
    unsafeAtomicAdd(p + 3, v.w * w);
}

__global__ __launch_bounds__(256) void softmax_rows(float* __restrict__ out) {
    int wave = (blockIdx.x * 256 + threadIdx.x) >> 6;
    int lane = threadIdx.x & 63;
    if (wave >= M_NODES) return;
    size_t idx = (size_t)wave * N_OUT_C + lane;
    float v = out[idx];
    float m = v;
    #pragma unroll
    for (int off = 32; off > 0; off >>= 1)
        m = fmaxf(m, __shfl_xor(m, off));
    float ev = __expf(v - m);
    float sum = ev;
    #pragma unroll
    for (int off = 32; off > 0; off >>= 1)
        sum += __shfl_xor(sum, off);
    out[idx] = ev / sum;
}

// ---------------------------------------------------------------------------
extern "C" void kernel_launch(void* const* d_in, const int* in_sizes, int n_in,
                              void* d_out, int out_size, void* d_ws, size_t ws_size,
                              hipStream_t stream) {
    const float* x    = (const float*)d_in[0];
    const int*   esrc = (const int*)d_in[1];
    const int*   edst = (const int*)d_in[2];
    const float* ew   = (const float*)d_in[3];
    const float* W    = (const float*)d_in[4];
    float* out = (float*)d_out;

    // workspace layout (16B-aligned chunks)
    char* ws = (char*)d_ws;
    size_t off_h      = 0;
    size_t sz_h       = (size_t)M_NODES * N_OUT_C * sizeof(float);      // 25.6 MB
    size_t off_deg    = (off_h + sz_h + 15) & ~15ull;
    size_t sz_deg     = (size_t)M_NODES * sizeof(int);                  // 400 KB
    size_t off_offs   = (off_deg + sz_deg + 15) & ~15ull;
    size_t sz_offs    = (size_t)(M_NODES + 4) * sizeof(int);
    size_t off_cur    = (off_offs + sz_offs + 15) & ~15ull;
    size_t sz_cur     = (size_t)(M_NODES + 4) * sizeof(int);
    size_t off_bsum   = (off_cur + sz_cur + 15) & ~15ull;
    size_t sz_bsum    = (size_t)SCAN_BLOCKS * sizeof(int);
    size_t off_boff   = (off_bsum + sz_bsum + 15) & ~15ull;
    size_t sz_boff    = (size_t)SCAN_BLOCKS * sizeof(int);
    size_t off_csr    = (off_boff + sz_boff + 15) & ~15ull;
    size_t sz_csr     = (size_t)N_EDGES_C * sizeof(int2);               // 12.8 MB
    size_t needed     = off_csr + sz_csr;

    float* h = (float*)(ws + off_h);

    gemm_xw<<<(M_NODES + 63) / 64, 256, 0, stream>>>(x, W, h);

    if (ws_size >= needed) {
        int*  deg     = (int*)(ws + off_deg);
        int*  offsets = (int*)(ws + off_offs);
        int*  cursor  = (int*)(ws + off_cur);
        int*  bsums   = (int*)(ws + off_bsum);
        int*  boffs   = (int*)(ws + off_boff);
        int2* csr     = (int2*)(ws + off_csr);

        hipMemsetAsync(deg, 0, sz_deg, stream);
        hist_dst<<<(N_EDGES_C + 255) / 256, 256, 0, stream>>>(edst, deg);
        scan_pass1<<<SCAN_BLOCKS, 256, 0, stream>>>(deg, bsums);
        scan_pass2<<<1, 128, 0, stream>>>(bsums, boffs, offsets);
        scan_pass3<<<SCAN_BLOCKS, 256, 0, stream>>>(deg, boffs, offsets, cursor);
        fill_csr<<<(N_EDGES_C + 255) / 256, 256, 0, stream>>>(esrc, edst, ew, cursor, csr);
        gather_softmax<<<(M_NODES * 64 + 255) / 256, 256, 0, stream>>>(offsets, csr, h, out);
    } else {
        // fallback: atomic scatter (R1 path)
        hipMemsetAsync(d_out, 0, (size_t)M_NODES * N_OUT_C * sizeof(float), stream);
        scatter_edges<<<(N_EDGES_C * 16 + 255) / 256, 256, 0, stream>>>(esrc, edst, ew, h, out);
        softmax_rows<<<(M_NODES + 3) / 4, 256, 0, stream>>>(out);
    }
}

// Round 4
// 561.781 us; speedup vs baseline: 3.0259x; 1.0390x over previous
//
#include <hip/hip_runtime.h>

#define M_NODES 100000
#define K_FEAT 512
#define N_OUT_C 64
#define N_EDGES_C 1600000

#define SCAN_CHUNK 1024
#define SCAN_BLOCKS ((M_NODES + SCAN_CHUNK - 1) / SCAN_CHUNK)   // 98

typedef __attribute__((ext_vector_type(8))) short short8;
typedef __attribute__((ext_vector_type(4))) float floatx4;

// fp32 -> bf16 round-to-nearest-even
static __device__ __forceinline__ unsigned short f2bf(float f) {
    unsigned int u = __float_as_uint(f);
    u += 0x7fffu + ((u >> 16) & 1u);
    return (unsigned short)(u >> 16);
}

// ---------------------------------------------------------------------------
// W[512][64] fp32 -> Wb bf16 in frag-swizzled layout [kblk=k/8][n][j=k%8]
// so a B-fragment (8 bf16, k=quad*8+j, n=lane&15) is one 16-B load.
// ---------------------------------------------------------------------------
__global__ __launch_bounds__(256) void conv_w(const float* __restrict__ W,
                                              unsigned short* __restrict__ Wb) {
    int id = blockIdx.x * 256 + threadIdx.x;          // 32768 total
    if (id >= K_FEAT * N_OUT_C) return;
    int k = id >> 6;
    int n = id & 63;
    Wb[((size_t)(k >> 3) * 64 + n) * 8 + (k & 7)] = f2bf(W[(size_t)k * 64 + n]);
}

// ---------------------------------------------------------------------------
// MFMA GEMM: h[M,64] = x[M,512] @ W[512,64], bf16 inputs, fp32 accumulate.
// One wave per 16 rows. No LDS, no barriers — pure stream of x.
//   A-frag: lane holds A[m=lane&15][k=k0+quad*8+j], built from 2 dwordx4 + cvt
//   B-frag: one short8 load from swizzled Wb per n-quarter
//   D: col=lane&15, row=quad*4+reg
// ---------------------------------------------------------------------------
__global__ __launch_bounds__(256) void gemm_mfma(const float* __restrict__ x,
                                                 const unsigned short* __restrict__ Wb,
                                                 float* __restrict__ h) {
    const int wid  = (blockIdx.x * 256 + threadIdx.x) >> 6;   // wave id = row tile
    const int lane = threadIdx.x & 63;
    if (wid >= M_NODES / 16) return;

    const int m    = lane & 15;
    const int quad = lane >> 4;
    const int rowBase = wid * 16;

    floatx4 acc0 = {0.f, 0.f, 0.f, 0.f};
    floatx4 acc1 = {0.f, 0.f, 0.f, 0.f};
    floatx4 acc2 = {0.f, 0.f, 0.f, 0.f};
    floatx4 acc3 = {0.f, 0.f, 0.f, 0.f};

    const float* aRow = x + (size_t)(rowBase + m) * K_FEAT + quad * 8;

    for (int k0 = 0; k0 < K_FEAT; k0 += 32) {
        float4 p0 = *(const float4*)(aRow + k0);
        float4 p1 = *(const float4*)(aRow + k0 + 4);
        short8 a;
        a[0] = (short)f2bf(p0.x); a[1] = (short)f2bf(p0.y);
        a[2] = (short)f2bf(p0.z); a[3] = (short)f2bf(p0.w);
        a[4] = (short)f2bf(p1.x); a[5] = (short)f2bf(p1.y);
        a[6] = (short)f2bf(p1.z); a[7] = (short)f2bf(p1.w);

        const unsigned short* wbase = Wb + (size_t)((k0 >> 3) + quad) * 512 + m * 8;
        short8 b0 = *(const short8*)(wbase + 0 * 128);
        short8 b1 = *(const short8*)(wbase + 1 * 128);
        short8 b2 = *(const short8*)(wbase + 2 * 128);
        short8 b3 = *(const short8*)(wbase + 3 * 128);

        acc0 = __builtin_amdgcn_mfma_f32_16x16x32_bf16(a, b0, acc0, 0, 0, 0);
        acc1 = __builtin_amdgcn_mfma_f32_16x16x32_bf16(a, b1, acc1, 0, 0, 0);
        acc2 = __builtin_amdgcn_mfma_f32_16x16x32_bf16(a, b2, acc2, 0, 0, 0);
        acc3 = __builtin_amdgcn_mfma_f32_16x16x32_bf16(a, b3, acc3, 0, 0, 0);
    }

    // D layout: row = quad*4 + r, col = q*16 + m
    float* hb = h + (size_t)(rowBase + quad * 4) * N_OUT_C + m;
    #pragma unroll
    for (int r = 0; r < 4; r++) {
        hb[(size_t)r * N_OUT_C + 0]  = acc0[r];
        hb[(size_t)r * N_OUT_C + 16] = acc1[r];
        hb[(size_t)r * N_OUT_C + 32] = acc2[r];
        hb[(size_t)r * N_OUT_C + 48] = acc3[r];
    }
}

// ---------------------------------------------------------------------------
// CSR build: histogram of edge destinations (int4-vectorized)
// ---------------------------------------------------------------------------
__global__ __launch_bounds__(256) void hist_dst(const int* __restrict__ edst,
                                                int* __restrict__ deg) {
    int e4 = (blockIdx.x * 256 + threadIdx.x) * 4;
    if (e4 >= N_EDGES_C) return;
    int4 d = *(const int4*)&edst[e4];
    atomicAdd(&deg[d.x], 1);
    atomicAdd(&deg[d.y], 1);
    atomicAdd(&deg[d.z], 1);
    atomicAdd(&deg[d.w], 1);
}

// ---------------------------------------------------------------------------
// Multi-block exclusive scan of deg -> offsets, cursor
// ---------------------------------------------------------------------------
__global__ __launch_bounds__(256) void scan_pass1(const int* __restrict__ deg,
                                                  int* __restrict__ bsums) {
    __shared__ int red[4];
    int base = blockIdx.x * SCAN_CHUNK + threadIdx.x * 4;
    int s = 0;
    if (base < M_NODES) {
        int4 v = *(const int4*)&deg[base];
        s = v.x + v.y + v.z + v.w;
    }
    #pragma unroll
    for (int off = 32; off > 0; off >>= 1) s += __shfl_xor(s, off);
    int wv = threadIdx.x >> 6;
    if ((threadIdx.x & 63) == 0) red[wv] = s;
    __syncthreads();
    if (threadIdx.x == 0)
        bsums[blockIdx.x] = red[0] + red[1] + red[2] + red[3];
}

__global__ __launch_bounds__(128) void scan_pass2(const int* __restrict__ bsums,
                                                  int* __restrict__ boffs,
                                                  int* __restrict__ offsets) {
    __shared__ int sh[128];
    int t = threadIdx.x;
    int v = (t < SCAN_BLOCKS) ? bsums[t] : 0;
    sh[t] = v;
    __syncthreads();
    #pragma unroll
    for (int off = 1; off < 128; off <<= 1) {
        int u = (t >= off) ? sh[t - off] : 0;
        __syncthreads();
        sh[t] += u;
        __syncthreads();
    }
    if (t < SCAN_BLOCKS) boffs[t] = sh[t] - v;
    if (t == 127) offsets[M_NODES] = sh[127];
}

__global__ __launch_bounds__(256) void scan_pass3(const int* __restrict__ deg,
                                                  const int* __restrict__ boffs,
                                                  int* __restrict__ offsets,
                                                  int* __restrict__ cursor) {
    __shared__ int sh[256];
    int t = threadIdx.x;
    int base = blockIdx.x * SCAN_CHUNK + t * 4;

    int4 v = make_int4(0, 0, 0, 0);
    if (base < M_NODES) v = *(const int4*)&deg[base];
    int s = v.x + v.y + v.z + v.w;

    sh[t] = s;
    __syncthreads();
    #pragma unroll
    for (int off = 1; off < 256; off <<= 1) {
        int u = (t >= off) ? sh[t - off] : 0;
        __syncthreads();
        sh[t] += u;
        __syncthreads();
    }
    int prefix = boffs[blockIdx.x] + sh[t] - s;

    if (base < M_NODES) {
        int4 o;
        o.x = prefix;
        o.y = o.x + v.x;
        o.z = o.y + v.y;
        o.w = o.z + v.z;
        *(int4*)&offsets[base] = o;
        *(int4*)&cursor[base]  = o;
    }
}

// ---------------------------------------------------------------------------
// Fill CSR (int4-vectorized reads)
// ---------------------------------------------------------------------------
__global__ __launch_bounds__(256) void fill_csr(const int* __restrict__ esrc,
                                                const int* __restrict__ edst,
                                                const float* __restrict__ ew,
                                                int* __restrict__ cursor,
                                                int2* __restrict__ csr) {
    int e4 = (blockIdx.x * 256 + threadIdx.x) * 4;
    if (e4 >= N_EDGES_C) return;
    int4   s = *(const int4*)&esrc[e4];
    int4   d = *(const int4*)&edst[e4];
    float4 w = *(const float4*)&ew[e4];
    int p;
    p = atomicAdd(&cursor[d.x], 1); csr[p] = make_int2(s.x, __float_as_int(w.x));
    p = atomicAdd(&cursor[d.y], 1); csr[p] = make_int2(s.y, __float_as_int(w.y));
    p = atomicAdd(&cursor[d.z], 1); csr[p] = make_int2(s.z, __float_as_int(w.z));
    p = atomicAdd(&cursor[d.w], 1); csr[p] = make_int2(s.w, __float_as_int(w.w));
}

// ---------------------------------------------------------------------------
// Gather + softmax fused: one wave per node.
// Lane layout: g = lane>>4 (edge slot, 4 edges in flight), c4 = lane&15
// (channel group, float4 -> 64 channels per 16 lanes). No per-edge shuffles.
// ---------------------------------------------------------------------------
__global__ __launch_bounds__(256) void gather_softmax(const int* __restrict__ offsets,
                                                      const int2* __restrict__ csr,
                                                      const float* __restrict__ h,
                                                      float* __restrict__ out) {
    int node = (blockIdx.x * 256 + threadIdx.x) >> 6;
    int lane = threadIdx.x & 63;
    if (node >= M_NODES) return;

    const int g  = lane >> 4;
    const int c4 = lane & 15;

    int start = offsets[node];
    int end   = offsets[node + 1];

    float4 acc = make_float4(0.f, 0.f, 0.f, 0.f);
    for (int base = start; base < end; base += 4) {
        int e = base + g;
        if (e < end) {
            int2 q = csr[e];                     // 16-lane broadcast load
            float w = __int_as_float(q.y);
            float4 v = *(const float4*)&h[(size_t)q.x * N_OUT_C + c4 * 4];
            acc.x += w * v.x;
            acc.y += w * v.y;
            acc.z += w * v.z;
            acc.w += w * v.w;
        }
    }

    // reduce across the 4 edge-groups (lanes differing in bits 4,5)
    #pragma unroll
    for (int off = 16; off < 64; off <<= 1) {
        acc.x += __shfl_xor(acc.x, off);
        acc.y += __shfl_xor(acc.y, off);
        acc.z += __shfl_xor(acc.z, off);
        acc.w += __shfl_xor(acc.w, off);
    }

    // softmax over 64 channels (spread as float4 over 16 lanes, replicated x4)
    float m = fmaxf(fmaxf(acc.x, acc.y), fmaxf(acc.z, acc.w));
    #pragma unroll
    for (int off = 1; off < 16; off <<= 1)
        m = fmaxf(m, __shfl_xor(m, off));

    float4 ev;
    ev.x = __expf(acc.x - m);
    ev.y = __expf(acc.y - m);
    ev.z = __expf(acc.z - m);
    ev.w = __expf(acc.w - m);

    float sum = ev.x + ev.y + ev.z + ev.w;
    #pragma unroll
    for (int off = 1; off < 16; off <<= 1)
        sum += __shfl_xor(sum, off);

    float inv = 1.0f / sum;
    if (g == 0) {
        float4 o = make_float4(ev.x * inv, ev.y * inv, ev.z * inv, ev.w * inv);
        *(float4*)&out[(size_t)node * N_OUT_C + c4 * 4] = o;
    }
}

// ---------------------------------------------------------------------------
// Fallback path kernels (fp32 GEMM + atomic scatter) — used only if ws too small
// ---------------------------------------------------------------------------
__global__ __launch_bounds__(256) void gemm_xw(const float* __restrict__ x,
                                               const float* __restrict__ W,
                                               float* __restrict__ h) {
    __shared__ float As[64][33];
    __shared__ float Bs[32][64];
    const int t  = threadIdx.x;
    const int tx = t & 15;
    const int ty = t >> 4;
    const int rowBase = blockIdx.x * 64;
    float acc[4][4] = {{0.f}};
    for (int k0 = 0; k0 < K_FEAT; k0 += 32) {
        #pragma unroll
        for (int i = 0; i < 2; i++) {
            int f = t + i * 256;
            int r = f >> 3, c4 = f & 7;
            int grow = rowBase + r;
            float4 v = make_float4(0.f, 0.f, 0.f, 0.f);
            if (grow < M_NODES)
                v = *(const float4*)&x[(size_t)grow * K_FEAT + k0 + c4 * 4];
            As[r][c4 * 4 + 0] = v.x; As[r][c4 * 4 + 1] = v.y;
            As[r][c4 * 4 + 2] = v.z; As[r][c4 * 4 + 3] = v.w;
        }
        #pragma unroll
        for (int i = 0; i < 2; i++) {
            int f = t + i * 256;
            ((float4*)Bs)[f] = ((const float4*)(W + (size_t)k0 * N_OUT_C))[f];
        }
        __syncthreads();
        #pragma unroll
        for (int k = 0; k < 32; k++) {
            float a0 = As[ty * 4 + 0][k], a1 = As[ty * 4 + 1][k];
            float a2 = As[ty * 4 + 2][k], a3 = As[ty * 4 + 3][k];
            float4 b = *(float4*)&Bs[k][tx * 4];
            acc[0][0] += a0 * b.x; acc[0][1] += a0 * b.y; acc[0][2] += a0 * b.z; acc[0][3] += a0 * b.w;
            acc[1][0] += a1 * b.x; acc[1][1] += a1 * b.y; acc[1][2] += a1 * b.z; acc[1][3] += a1 * b.w;
            acc[2][0] += a2 * b.x; acc[2][1] += a2 * b.y; acc[2][2] += a2 * b.z; acc[2][3] += a2 * b.w;
            acc[3][0] += a3 * b.x; acc[3][1] += a3 * b.y; acc[3][2] += a3 * b.z; acc[3][3] += a3 * b.w;
        }
        __syncthreads();
    }
    #pragma unroll
    for (int i = 0; i < 4; i++) {
        int row = rowBase + ty * 4 + i;
        if (row < M_NODES)
            *(float4*)&h[(size_t)row * N_OUT_C + tx * 4] =
                make_float4(acc[i][0], acc[i][1], acc[i][2], acc[i][3]);
    }
}

__global__ __launch_bounds__(256) void scatter_edges(const int* __restrict__ esrc,
                                                     const int* __restrict__ edst,
                                                     const float* __restrict__ ew,
                                                     const float* __restrict__ h,
                                                     float* __restrict__ agg) {
    int tid = blockIdx.x * 256 + threadIdx.x;
    int e = tid >> 4;
    int g = tid & 15;
    if (e >= N_EDGES_C) return;
    int s = esrc[e], d = edst[e];
    float w = ew[e];
    float4 v = *(const float4*)&h[(size_t)s * N_OUT_C + g * 4];
    float* p = agg + (size_t)d * N_OUT_C + g * 4;
    unsafeAtomicAdd(p + 0, v.x * w);
    unsafeAtomicAdd(p + 1, v.y * w);
    unsafeAtomicAdd(p + 2, v.z * w);
    unsafeAtomicAdd(p + 3, v.w * w);
}

__global__ __launch_bounds__(256) void softmax_rows(float* __restrict__ out) {
    int wave = (blockIdx.x * 256 + threadIdx.x) >> 6;
    int lane = threadIdx.x & 63;
    if (wave >= M_NODES) return;
    size_t idx = (size_t)wave * N_OUT_C + lane;
    float v = out[idx];
    float m = v;
    #pragma unroll
    for (int off = 32; off > 0; off >>= 1) m = fmaxf(m, __shfl_xor(m, off));
    float ev = __expf(v - m);
    float sum = ev;
    #pragma unroll
    for (int off = 32; off > 0; off >>= 1) sum += __shfl_xor(sum, off);
    out[idx] = ev / sum;
}

// ---------------------------------------------------------------------------
extern "C" void kernel_launch(void* const* d_in, const int* in_sizes, int n_in,
                              void* d_out, int out_size, void* d_ws, size_t ws_size,
                              hipStream_t stream) {
    const float* x    = (const float*)d_in[0];
    const int*   esrc = (const int*)d_in[1];
    const int*   edst = (const int*)d_in[2];
    const float* ew   = (const float*)d_in[3];
    const float* W    = (const float*)d_in[4];
    float* out = (float*)d_out;

    char* ws = (char*)d_ws;
    size_t off_h    = 0;
    size_t sz_h     = (size_t)M_NODES * N_OUT_C * sizeof(float);        // 25.6 MB
    size_t off_deg  = (off_h + sz_h + 15) & ~15ull;
    size_t sz_deg   = (size_t)M_NODES * sizeof(int);
    size_t off_offs = (off_deg + sz_deg + 15) & ~15ull;
    size_t sz_offs  = (size_t)(M_NODES + 4) * sizeof(int);
    size_t off_cur  = (off_offs + sz_offs + 15) & ~15ull;
    size_t sz_cur   = (size_t)(M_NODES + 4) * sizeof(int);
    size_t off_bsum = (off_cur + sz_cur + 15) & ~15ull;
    size_t sz_bsum  = (size_t)SCAN_BLOCKS * sizeof(int);
    size_t off_boff = (off_bsum + sz_bsum + 15) & ~15ull;
    size_t sz_boff  = (size_t)SCAN_BLOCKS * sizeof(int);
    size_t off_csr  = (off_boff + sz_boff + 15) & ~15ull;
    size_t sz_csr   = (size_t)N_EDGES_C * sizeof(int2);                 // 12.8 MB
    size_t off_wb   = (off_csr + sz_csr + 15) & ~15ull;
    size_t sz_wb    = (size_t)K_FEAT * N_OUT_C * sizeof(unsigned short); // 64 KB
    size_t needed   = off_wb + sz_wb;

    float* h = (float*)(ws + off_h);

    if (ws_size >= needed) {
        int*  deg     = (int*)(ws + off_deg);
        int*  offsets = (int*)(ws + off_offs);
        int*  cursor  = (int*)(ws + off_cur);
        int*  bsums   = (int*)(ws + off_bsum);
        int*  boffs   = (int*)(ws + off_boff);
        int2* csr     = (int2*)(ws + off_csr);
        unsigned short* Wb = (unsigned short*)(ws + off_wb);

        conv_w<<<(K_FEAT * N_OUT_C + 255) / 256, 256, 0, stream>>>(W, Wb);
        gemm_mfma<<<(M_NODES / 16 + 3) / 4, 256, 0, stream>>>(x, Wb, h);

        hipMemsetAsync(deg, 0, sz_deg, stream);
        hist_dst<<<(N_EDGES_C / 4 + 255) / 256, 256, 0, stream>>>(edst, deg);
        scan_pass1<<<SCAN_BLOCKS, 256, 0, stream>>>(deg, bsums);
        scan_pass2<<<1, 128, 0, stream>>>(bsums, boffs, offsets);
        scan_pass3<<<SCAN_BLOCKS, 256, 0, stream>>>(deg, boffs, offsets, cursor);
        fill_csr<<<(N_EDGES_C / 4 + 255) / 256, 256, 0, stream>>>(esrc, edst, ew, cursor, csr);
        gather_softmax<<<(M_NODES * 64 + 255) / 256, 256, 0, stream>>>(offsets, csr, h, out);
    } else {
        // fallback: fp32 gemm + atomic scatter
        hipMemsetAsync(d_out, 0, (size_t)M_NODES * N_OUT_C * sizeof(float), stream);
        gemm_xw<<<(M_NODES + 63) / 64, 256, 0, stream>>>(x, W, h);
        scatter_edges<<<(N_EDGES_C * 16 + 255) / 256, 256, 0, stream>>>(esrc, edst, ew, h, out);
        softmax_rows<<<(M_NODES + 3) / 4, 256, 0, stream>>>(out);
    }
}

// Round 5
// 549.733 us; speedup vs baseline: 3.0922x; 1.0219x over previous
//
#include <hip/hip_runtime.h>

#define M_NODES 100000
#define K_FEAT 512
#define N_OUT_C 64
#define N_EDGES_C 1600000

#define SCAN_CHUNK 1024
#define SCAN_BLOCKS ((M_NODES + SCAN_CHUNK - 1) / SCAN_CHUNK)   // 98

#define GEMM_BLOCKS ((M_NODES / 16 + 3) / 4)                    // 1563
#define FILL_EPT 8
#define FILL_BLOCKS ((N_EDGES_C / FILL_EPT + 255) / 256)        // 782
#define HIST_EPT 8
#define HIST_BLOCKS ((N_EDGES_C / HIST_EPT + 255) / 256)        // 782

typedef __attribute__((ext_vector_type(8))) short short8;
typedef __attribute__((ext_vector_type(4))) float floatx4;

// fp32 -> bf16 round-to-nearest-even
static __device__ __forceinline__ unsigned short f2bf(float f) {
    unsigned int u = __float_as_uint(f);
    u += 0x7fffu + ((u >> 16) & 1u);
    return (unsigned short)(u >> 16);
}

// ---------------------------------------------------------------------------
// conv_w + zero deg: W[512][64] fp32 -> Wb bf16 frag-swizzled [k/8][n][k%8];
// also zeroes deg[] (grid-stride). 128 blocks x 256 = 32768 threads.
// ---------------------------------------------------------------------------
__global__ __launch_bounds__(256) void conv_w_zero(const float* __restrict__ W,
                                                   unsigned short* __restrict__ Wb,
                                                   int* __restrict__ deg) {
    int id = blockIdx.x * 256 + threadIdx.x;
    for (int i = id; i < M_NODES; i += 32768) deg[i] = 0;
    if (id < K_FEAT * N_OUT_C) {
        int k = id >> 6;
        int n = id & 63;
        Wb[((size_t)(k >> 3) * 64 + n) * 8 + (k & 7)] = f2bf(W[(size_t)k * 64 + n]);
    }
}

// ---------------------------------------------------------------------------
// Histogram of edge destinations: 8 edges/thread, fire-and-forget atomics.
// ---------------------------------------------------------------------------
__global__ __launch_bounds__(256) void hist_dst(const int* __restrict__ edst,
                                                int* __restrict__ deg) {
    int base = (blockIdx.x * 256 + threadIdx.x) * HIST_EPT;
    if (base >= N_EDGES_C) return;
    int4 d0 = *(const int4*)&edst[base];
    int4 d1 = *(const int4*)&edst[base + 4];
    atomicAdd(&deg[d0.x], 1);
    atomicAdd(&deg[d0.y], 1);
    atomicAdd(&deg[d0.z], 1);
    atomicAdd(&deg[d0.w], 1);
    atomicAdd(&deg[d1.x], 1);
    atomicAdd(&deg[d1.y], 1);
    atomicAdd(&deg[d1.z], 1);
    atomicAdd(&deg[d1.w], 1);
}

// ---------------------------------------------------------------------------
// Multi-block exclusive scan of deg -> offsets, cursor
// ---------------------------------------------------------------------------
__global__ __launch_bounds__(256) void scan_pass1(const int* __restrict__ deg,
                                                  int* __restrict__ bsums) {
    __shared__ int red[4];
    int base = blockIdx.x * SCAN_CHUNK + threadIdx.x * 4;
    int s = 0;
    if (base < M_NODES) {
        int4 v = *(const int4*)&deg[base];
        s = v.x + v.y + v.z + v.w;
    }
    #pragma unroll
    for (int off = 32; off > 0; off >>= 1) s += __shfl_xor(s, off);
    int wv = threadIdx.x >> 6;
    if ((threadIdx.x & 63) == 0) red[wv] = s;
    __syncthreads();
    if (threadIdx.x == 0)
        bsums[blockIdx.x] = red[0] + red[1] + red[2] + red[3];
}

__global__ __launch_bounds__(128) void scan_pass2(const int* __restrict__ bsums,
                                                  int* __restrict__ boffs,
                                                  int* __restrict__ offsets) {
    __shared__ int sh[128];
    int t = threadIdx.x;
    int v = (t < SCAN_BLOCKS) ? bsums[t] : 0;
    sh[t] = v;
    __syncthreads();
    #pragma unroll
    for (int off = 1; off < 128; off <<= 1) {
        int u = (t >= off) ? sh[t - off] : 0;
        __syncthreads();
        sh[t] += u;
        __syncthreads();
    }
    if (t < SCAN_BLOCKS) boffs[t] = sh[t] - v;
    if (t == 127) offsets[M_NODES] = sh[127];
}

__global__ __launch_bounds__(256) void scan_pass3(const int* __restrict__ deg,
                                                  const int* __restrict__ boffs,
                                                  int* __restrict__ offsets,
                                                  int* __restrict__ cursor) {
    __shared__ int sh[256];
    int t = threadIdx.x;
    int base = blockIdx.x * SCAN_CHUNK + t * 4;

    int4 v = make_int4(0, 0, 0, 0);
    if (base < M_NODES) v = *(const int4*)&deg[base];
    int s = v.x + v.y + v.z + v.w;

    sh[t] = s;
    __syncthreads();
    #pragma unroll
    for (int off = 1; off < 256; off <<= 1) {
        int u = (t >= off) ? sh[t - off] : 0;
        __syncthreads();
        sh[t] += u;
        __syncthreads();
    }
    int prefix = boffs[blockIdx.x] + sh[t] - s;

    if (base < M_NODES) {
        int4 o;
        o.x = prefix;
        o.y = o.x + v.x;
        o.z = o.y + v.y;
        o.w = o.z + v.z;
        *(int4*)&offsets[base] = o;
        *(int4*)&cursor[base]  = o;
    }
}

// ---------------------------------------------------------------------------
// Fused dispatch: blocks [0, FILL_BLOCKS) do fill_csr (8 edges/thread,
// atomics batched before stores); blocks [FILL_BLOCKS, +GEMM_BLOCKS) do the
// bf16-MFMA GEMM. The two are independent and use disjoint pipes
// (fill: L3 atomic latency; gemm: HBM stream + MFMA) so they co-schedule.
// ---------------------------------------------------------------------------
__device__ __forceinline__ void fill_body(int bidx,
                                          const int* __restrict__ esrc,
                                          const int* __restrict__ edst,
                                          const float* __restrict__ ew,
                                          int* __restrict__ cursor,
                                          int2* __restrict__ csr) {
    int base = (bidx * 256 + threadIdx.x) * FILL_EPT;
    if (base >= N_EDGES_C) return;
    int4   s0 = *(const int4*)&esrc[base];
    int4   s1 = *(const int4*)&esrc[base + 4];
    int4   d0 = *(const int4*)&edst[base];
    int4   d1 = *(const int4*)&edst[base + 4];
    float4 w0 = *(const float4*)&ew[base];
    float4 w1 = *(const float4*)&ew[base + 4];

    int dd[8] = {d0.x, d0.y, d0.z, d0.w, d1.x, d1.y, d1.z, d1.w};
    int ss[8] = {s0.x, s0.y, s0.z, s0.w, s1.x, s1.y, s1.z, s1.w};
    float wwv[8] = {w0.x, w0.y, w0.z, w0.w, w1.x, w1.y, w1.z, w1.w};

    int pos[8];
    #pragma unroll
    for (int i = 0; i < 8; i++) pos[i] = atomicAdd(&cursor[dd[i]], 1);
    #pragma unroll
    for (int i = 0; i < 8; i++) csr[pos[i]] = make_int2(ss[i], __float_as_int(wwv[i]));
}

__device__ __forceinline__ void gemm_body(int bidx,
                                          const float* __restrict__ x,
                                          const unsigned short* __restrict__ Wb,
                                          float* __restrict__ h) {
    const int wid  = (bidx * 256 + (int)threadIdx.x) >> 6;
    const int lane = threadIdx.x & 63;
    if (wid >= M_NODES / 16) return;

    const int m    = lane & 15;
    const int quad = lane >> 4;
    const int rowBase = wid * 16;

    floatx4 acc0 = {0.f, 0.f, 0.f, 0.f};
    floatx4 acc1 = {0.f, 0.f, 0.f, 0.f};
    floatx4 acc2 = {0.f, 0.f, 0.f, 0.f};
    floatx4 acc3 = {0.f, 0.f, 0.f, 0.f};

    const float* aRow = x + (size_t)(rowBase + m) * K_FEAT + quad * 8;

    for (int k0 = 0; k0 < K_FEAT; k0 += 32) {
        float4 p0 = *(const float4*)(aRow + k0);
        float4 p1 = *(const float4*)(aRow + k0 + 4);
        short8 a;
        a[0] = (short)f2bf(p0.x); a[1] = (short)f2bf(p0.y);
        a[2] = (short)f2bf(p0.z); a[3] = (short)f2bf(p0.w);
        a[4] = (short)f2bf(p1.x); a[5] = (short)f2bf(p1.y);
        a[6] = (short)f2bf(p1.z); a[7] = (short)f2bf(p1.w);

        const unsigned short* wbase = Wb + (size_t)((k0 >> 3) + quad) * 512 + m * 8;
        short8 b0 = *(const short8*)(wbase + 0 * 128);
        short8 b1 = *(const short8*)(wbase + 1 * 128);
        short8 b2 = *(const short8*)(wbase + 2 * 128);
        short8 b3 = *(const short8*)(wbase + 3 * 128);

        acc0 = __builtin_amdgcn_mfma_f32_16x16x32_bf16(a, b0, acc0, 0, 0, 0);
        acc1 = __builtin_amdgcn_mfma_f32_16x16x32_bf16(a, b1, acc1, 0, 0, 0);
        acc2 = __builtin_amdgcn_mfma_f32_16x16x32_bf16(a, b2, acc2, 0, 0, 0);
        acc3 = __builtin_amdgcn_mfma_f32_16x16x32_bf16(a, b3, acc3, 0, 0, 0);
    }

    float* hb = h + (size_t)(rowBase + quad * 4) * N_OUT_C + m;
    #pragma unroll
    for (int r = 0; r < 4; r++) {
        hb[(size_t)r * N_OUT_C + 0]  = acc0[r];
        hb[(size_t)r * N_OUT_C + 16] = acc1[r];
        hb[(size_t)r * N_OUT_C + 32] = acc2[r];
        hb[(size_t)r * N_OUT_C + 48] = acc3[r];
    }
}

__global__ __launch_bounds__(256) void fill_and_gemm(const int* __restrict__ esrc,
                                                     const int* __restrict__ edst,
                                                     const float* __restrict__ ew,
                                                     int* __restrict__ cursor,
                                                     int2* __restrict__ csr,
                                                     const float* __restrict__ x,
                                                     const unsigned short* __restrict__ Wb,
                                                     float* __restrict__ h) {
    if (blockIdx.x < FILL_BLOCKS)
        fill_body(blockIdx.x, esrc, edst, ew, cursor, csr);
    else
        gemm_body(blockIdx.x - FILL_BLOCKS, x, Wb, h);
}

// ---------------------------------------------------------------------------
// Gather + softmax fused: one wave per node.
// Stage 64 edges of csr in one coalesced load; shuffle-broadcast to the four
// 16-lane groups; 4 independent h-gathers in flight per group.
// ---------------------------------------------------------------------------
__global__ __launch_bounds__(256) void gather_softmax(const int* __restrict__ offsets,
                                                      const int2* __restrict__ csr,
                                                      const float* __restrict__ h,
                                                      float* __restrict__ out) {
    int node = (blockIdx.x * 256 + threadIdx.x) >> 6;
    int lane = threadIdx.x & 63;
    if (node >= M_NODES) return;

    const int g  = lane >> 4;
    const int c4 = lane & 15;

    int start = offsets[node];
    int end   = offsets[node + 1];

    float4 acc = make_float4(0.f, 0.f, 0.f, 0.f);

    for (int chunk = start; chunk < end; chunk += 64) {
        int avail = min(64, end - chunk);
        int2 q = make_int2(0, 0);
        if (lane < avail) q = csr[chunk + lane];

        for (int j = 0; j < avail; j += 16) {
            #pragma unroll
            for (int st = 0; st < 4; st++) {
                int e = j + st * 4 + g;
                int   sx = __shfl(q.x, e);
                float wv = __shfl(__int_as_float(q.y), e);
                if (e < avail) {
                    float4 v = *(const float4*)&h[(size_t)sx * N_OUT_C + c4 * 4];
                    acc.x += wv * v.x;
                    acc.y += wv * v.y;
                    acc.z += wv * v.z;
                    acc.w += wv * v.w;
                }
            }
        }
    }

    // reduce across the 4 edge-groups (lanes differing in bits 4,5)
    #pragma unroll
    for (int off = 16; off < 64; off <<= 1) {
        acc.x += __shfl_xor(acc.x, off);
        acc.y += __shfl_xor(acc.y, off);
        acc.z += __shfl_xor(acc.z, off);
        acc.w += __shfl_xor(acc.w, off);
    }

    // softmax over 64 channels (float4 over 16 lanes)
    float m = fmaxf(fmaxf(acc.x, acc.y), fmaxf(acc.z, acc.w));
    #pragma unroll
    for (int off = 1; off < 16; off <<= 1)
        m = fmaxf(m, __shfl_xor(m, off));

    float4 ev;
    ev.x = __expf(acc.x - m);
    ev.y = __expf(acc.y - m);
    ev.z = __expf(acc.z - m);
    ev.w = __expf(acc.w - m);

    float sum = ev.x + ev.y + ev.z + ev.w;
    #pragma unroll
    for (int off = 1; off < 16; off <<= 1)
        sum += __shfl_xor(sum, off);

    float inv = 1.0f / sum;
    if (g == 0) {
        float4 o = make_float4(ev.x * inv, ev.y * inv, ev.z * inv, ev.w * inv);
        *(float4*)&out[(size_t)node * N_OUT_C + c4 * 4] = o;
    }
}

// ---------------------------------------------------------------------------
// Fallback path kernels (fp32 GEMM + atomic scatter) — used only if ws too small
// ---------------------------------------------------------------------------
__global__ __launch_bounds__(256) void gemm_xw(const float* __restrict__ x,
                                               const float* __restrict__ W,
                                               float* __restrict__ h) {
    __shared__ float As[64][33];
    __shared__ float Bs[32][64];
    const int t  = threadIdx.x;
    const int tx = t & 15;
    const int ty = t >> 4;
    const int rowBase = blockIdx.x * 64;
    float acc[4][4] = {{0.f}};
    for (int k0 = 0; k0 < K_FEAT; k0 += 32) {
        #pragma unroll
        for (int i = 0; i < 2; i++) {
            int f = t + i * 256;
            int r = f >> 3, c4 = f & 7;
            int grow = rowBase + r;
            float4 v = make_float4(0.f, 0.f, 0.f, 0.f);
            if (grow < M_NODES)
                v = *(const float4*)&x[(size_t)grow * K_FEAT + k0 + c4 * 4];
            As[r][c4 * 4 + 0] = v.x; As[r][c4 * 4 + 1] = v.y;
            As[r][c4 * 4 + 2] = v.z; As[r][c4 * 4 + 3] = v.w;
        }
        #pragma unroll
        for (int i = 0; i < 2; i++) {
            int f = t + i * 256;
            ((float4*)Bs)[f] = ((const float4*)(W + (size_t)k0 * N_OUT_C))[f];
        }
        __syncthreads();
        #pragma unroll
        for (int k = 0; k < 32; k++) {
            float a0 = As[ty * 4 + 0][k], a1 = As[ty * 4 + 1][k];
            float a2 = As[ty * 4 + 2][k], a3 = As[ty * 4 + 3][k];
            float4 b = *(float4*)&Bs[k][tx * 4];
            acc[0][0] += a0 * b.x; acc[0][1] += a0 * b.y; acc[0][2] += a0 * b.z; acc[0][3] += a0 * b.w;
            acc[1][0] += a1 * b.x; acc[1][1] += a1 * b.y; acc[1][2] += a1 * b.z; acc[1][3] += a1 * b.w;
            acc[2][0] += a2 * b.x; acc[2][1] += a2 * b.y; acc[2][2] += a2 * b.z; acc[2][3] += a2 * b.w;
            acc[3][0] += a3 * b.x; acc[3][1] += a3 * b.y; acc[3][2] += a3 * b.z; acc[3][3] += a3 * b.w;
        }
        __syncthreads();
    }
    #pragma unroll
    for (int i = 0; i < 4; i++) {
        int row = rowBase + ty * 4 + i;
        if (row < M_NODES)
            *(float4*)&h[(size_t)row * N_OUT_C + tx * 4] =
                make_float4(acc[i][0], acc[i][1], acc[i][2], acc[i][3]);
    }
}

__global__ __launch_bounds__(256) void scatter_edges(const int* __restrict__ esrc,
                                                     const int* __restrict__ edst,
                                                     const float* __restrict__ ew,
                                                     const float* __restrict__ h,
                                                     float* __restrict__ agg) {
    int tid = blockIdx.x * 256 + threadIdx.x;
    int e = tid >> 4;
    int g = tid & 15;
    if (e >= N_EDGES_C) return;
    int s = esrc[e], d = edst[e];
    float w = ew[e];
    float4 v = *(const float4*)&h[(size_t)s * N_OUT_C + g * 4];
    float* p = agg + (size_t)d * N_OUT_C + g * 4;
    unsafeAtomicAdd(p + 0, v.x * w);
    unsafeAtomicAdd(p + 1, v.y * w);
    unsafeAtomicAdd(p + 2, v.z * w);
    unsafeAtomicAdd(p + 3, v.w * w);
}

__global__ __launch_bounds__(256) void softmax_rows(float* __restrict__ out) {
    int wave = (blockIdx.x * 256 + threadIdx.x) >> 6;
    int lane = threadIdx.x & 63;
    if (wave >= M_NODES) return;
    size_t idx = (size_t)wave * N_OUT_C + lane;
    float v = out[idx];
    float m = v;
    #pragma unroll
    for (int off = 32; off > 0; off >>= 1) m = fmaxf(m, __shfl_xor(m, off));
    float ev = __expf(v - m);
    float sum = ev;
    #pragma unroll
    for (int off = 32; off > 0; off >>= 1) sum += __shfl_xor(sum, off);
    out[idx] = ev / sum;
}

// ---------------------------------------------------------------------------
extern "C" void kernel_launch(void* const* d_in, const int* in_sizes, int n_in,
                              void* d_out, int out_size, void* d_ws, size_t ws_size,
                              hipStream_t stream) {
    const float* x    = (const float*)d_in[0];
    const int*   esrc = (const int*)d_in[1];
    const int*   edst = (const int*)d_in[2];
    const float* ew   = (const float*)d_in[3];
    const float* W    = (const float*)d_in[4];
    float* out = (float*)d_out;

    char* ws = (char*)d_ws;
    size_t off_h    = 0;
    size_t sz_h     = (size_t)M_NODES * N_OUT_C * sizeof(float);        // 25.6 MB
    size_t off_deg  = (off_h + sz_h + 15) & ~15ull;
    size_t sz_deg   = (size_t)M_NODES * sizeof(int);
    size_t off_offs = (off_deg + sz_deg + 15) & ~15ull;
    size_t sz_offs  = (size_t)(M_NODES + 4) * sizeof(int);
    size_t off_cur  = (off_offs + sz_offs + 15) & ~15ull;
    size_t sz_cur   = (size_t)(M_NODES + 4) * sizeof(int);
    size_t off_bsum = (off_cur + sz_cur + 15) & ~15ull;
    size_t sz_bsum  = (size_t)SCAN_BLOCKS * sizeof(int);
    size_t off_boff = (off_bsum + sz_bsum + 15) & ~15ull;
    size_t sz_boff  = (size_t)SCAN_BLOCKS * sizeof(int);
    size_t off_csr  = (off_boff + sz_boff + 15) & ~15ull;
    size_t sz_csr   = (size_t)N_EDGES_C * sizeof(int2);                 // 12.8 MB
    size_t off_wb   = (off_csr + sz_csr + 15) & ~15ull;
    size_t sz_wb    = (size_t)K_FEAT * N_OUT_C * sizeof(unsigned short); // 64 KB
    size_t needed   = off_wb + sz_wb;

    float* h = (float*)(ws + off_h);

    if (ws_size >= needed) {
        int*  deg     = (int*)(ws + off_deg);
        int*  offsets = (int*)(ws + off_offs);
        int*  cursor  = (int*)(ws + off_cur);
        int*  bsums   = (int*)(ws + off_bsum);
        int*  boffs   = (int*)(ws + off_boff);
        int2* csr     = (int2*)(ws + off_csr);
        unsigned short* Wb = (unsigned short*)(ws + off_wb);

        conv_w_zero<<<128, 256, 0, stream>>>(W, Wb, deg);
        hist_dst<<<HIST_BLOCKS, 256, 0, stream>>>(edst, deg);
        scan_pass1<<<SCAN_BLOCKS, 256, 0, stream>>>(deg, bsums);
        scan_pass2<<<1, 128, 0, stream>>>(bsums, boffs, offsets);
        scan_pass3<<<SCAN_BLOCKS, 256, 0, stream>>>(deg, boffs, offsets, cursor);
        fill_and_gemm<<<FILL_BLOCKS + GEMM_BLOCKS, 256, 0, stream>>>(
            esrc, edst, ew, cursor, csr, x, Wb, h);
        gather_softmax<<<(M_NODES * 64 + 255) / 256, 256, 0, stream>>>(offsets, csr, h, out);
    } else {
        // fallback: fp32 gemm + atomic scatter
        hipMemsetAsync(d_out, 0, (size_t)M_NODES * N_OUT_C * sizeof(float), stream);
        gemm_xw<<<(M_NODES + 63) / 64, 256, 0, stream>>>(x, W, h);
        scatter_edges<<<(N_EDGES_C * 16 + 255) / 256, 256, 0, stream>>>(esrc, edst, ew, h, out);
        softmax_rows<<<(M_NODES + 3) / 4, 256, 0, stream>>>(out);
    }
}

// Round 6
// 464.577 us; speedup vs baseline: 3.6590x; 1.1833x over previous
//
#include <hip/hip_runtime.h>

#define M_NODES 100000
#define K_FEAT 512
#define N_OUT_C 64
#define N_EDGES_C 1600000

#define CAP 40                 // per-node csr slots; P(deg>40) ~ 2e-7/node
#define OVCAP 8192             // overflow entries (expected ~0 used)

#define SC_EPT 8
#define SC_BLOCKS ((N_EDGES_C / SC_EPT + 255) / 256)   // 782

typedef __attribute__((ext_vector_type(8))) short short8;
typedef __attribute__((ext_vector_type(4))) float floatx4;

// fp32 -> bf16 round-to-nearest-even
static __device__ __forceinline__ unsigned short f2bf(float f) {
    unsigned int u = __float_as_uint(f);
    u += 0x7fffu + ((u >> 16) & 1u);
    return (unsigned short)(u >> 16);
}
static __device__ __forceinline__ float bf2f(unsigned short u) {
    return __uint_as_float((unsigned int)u << 16);
}

// ---------------------------------------------------------------------------
// conv_w_zero: W[512][64] fp32 -> Wb bf16 frag-swizzled [k/8][n][k%8];
// zero deg[] and ov_cnt. 128 blocks x 256.
// ---------------------------------------------------------------------------
__global__ __launch_bounds__(256) void conv_w_zero(const float* __restrict__ W,
                                                   unsigned short* __restrict__ Wb,
                                                   int* __restrict__ deg,
                                                   int* __restrict__ ov_cnt) {
    int id = blockIdx.x * 256 + threadIdx.x;
    for (int i = id; i < M_NODES; i += 32768) deg[i] = 0;
    if (id == 0) *ov_cnt = 0;
    if (id < K_FEAT * N_OUT_C) {
        int k = id >> 6;
        int n = id & 63;
        Wb[((size_t)(k >> 3) * 64 + n) * 8 + (k & 7)] = f2bf(W[(size_t)k * 64 + n]);
    }
}

// ---------------------------------------------------------------------------
// MFMA GEMM: h[M,64] = x[M,512] @ W[512,64], bf16 in, fp32 acc, bf16 out.
// One wave per 16 rows, no LDS. (verified layout from R4/R5)
// ---------------------------------------------------------------------------
__global__ __launch_bounds__(256) void gemm_mfma(const float* __restrict__ x,
                                                 const unsigned short* __restrict__ Wb,
                                                 unsigned short* __restrict__ hb) {
    const int wid  = (blockIdx.x * 256 + (int)threadIdx.x) >> 6;
    const int lane = threadIdx.x & 63;
    if (wid >= M_NODES / 16) return;

    const int m    = lane & 15;
    const int quad = lane >> 4;
    const int rowBase = wid * 16;

    floatx4 acc0 = {0.f, 0.f, 0.f, 0.f};
    floatx4 acc1 = {0.f, 0.f, 0.f, 0.f};
    floatx4 acc2 = {0.f, 0.f, 0.f, 0.f};
    floatx4 acc3 = {0.f, 0.f, 0.f, 0.f};

    const float* aRow = x + (size_t)(rowBase + m) * K_FEAT + quad * 8;

    for (int k0 = 0; k0 < K_FEAT; k0 += 32) {
        float4 p0 = *(const float4*)(aRow + k0);
        float4 p1 = *(const float4*)(aRow + k0 + 4);
        short8 a;
        a[0] = (short)f2bf(p0.x); a[1] = (short)f2bf(p0.y);
        a[2] = (short)f2bf(p0.z); a[3] = (short)f2bf(p0.w);
        a[4] = (short)f2bf(p1.x); a[5] = (short)f2bf(p1.y);
        a[6] = (short)f2bf(p1.z); a[7] = (short)f2bf(p1.w);

        const unsigned short* wbase = Wb + (size_t)((k0 >> 3) + quad) * 512 + m * 8;
        short8 b0 = *(const short8*)(wbase + 0 * 128);
        short8 b1 = *(const short8*)(wbase + 1 * 128);
        short8 b2 = *(const short8*)(wbase + 2 * 128);
        short8 b3 = *(const short8*)(wbase + 3 * 128);

        acc0 = __builtin_amdgcn_mfma_f32_16x16x32_bf16(a, b0, acc0, 0, 0, 0);
        acc1 = __builtin_amdgcn_mfma_f32_16x16x32_bf16(a, b1, acc1, 0, 0, 0);
        acc2 = __builtin_amdgcn_mfma_f32_16x16x32_bf16(a, b2, acc2, 0, 0, 0);
        acc3 = __builtin_amdgcn_mfma_f32_16x16x32_bf16(a, b3, acc3, 0, 0, 0);
    }

    unsigned short* hp = hb + (size_t)(rowBase + quad * 4) * N_OUT_C + m;
    #pragma unroll
    for (int r = 0; r < 4; r++) {
        hp[(size_t)r * N_OUT_C + 0]  = f2bf(acc0[r]);
        hp[(size_t)r * N_OUT_C + 16] = f2bf(acc1[r]);
        hp[(size_t)r * N_OUT_C + 32] = f2bf(acc2[r]);
        hp[(size_t)r * N_OUT_C + 48] = f2bf(acc3[r]);
    }
}

// ---------------------------------------------------------------------------
// Direct scatter into fixed-capacity per-node rows (single pass, replaces
// hist + scan + fill). Overflow (deg>CAP, ~never) goes to a small list.
// ---------------------------------------------------------------------------
__global__ __launch_bounds__(256) void scatter_direct(const int* __restrict__ esrc,
                                                      const int* __restrict__ edst,
                                                      const float* __restrict__ ew,
                                                      int* __restrict__ deg,
                                                      int2* __restrict__ csr2,
                                                      int* __restrict__ ov_cnt,
                                                      int4* __restrict__ ov) {
    int base = (blockIdx.x * 256 + threadIdx.x) * SC_EPT;
    if (base >= N_EDGES_C) return;
    int4   s0 = *(const int4*)&esrc[base];
    int4   s1 = *(const int4*)&esrc[base + 4];
    int4   d0 = *(const int4*)&edst[base];
    int4   d1 = *(const int4*)&edst[base + 4];
    float4 w0 = *(const float4*)&ew[base];
    float4 w1 = *(const float4*)&ew[base + 4];

    int dd[8] = {d0.x, d0.y, d0.z, d0.w, d1.x, d1.y, d1.z, d1.w};
    int ss[8] = {s0.x, s0.y, s0.z, s0.w, s1.x, s1.y, s1.z, s1.w};
    float wwv[8] = {w0.x, w0.y, w0.z, w0.w, w1.x, w1.y, w1.z, w1.w};

    int r[8];
    #pragma unroll
    for (int i = 0; i < 8; i++) r[i] = atomicAdd(&deg[dd[i]], 1);
    #pragma unroll
    for (int i = 0; i < 8; i++) {
        if (r[i] < CAP) {
            csr2[(size_t)dd[i] * CAP + r[i]] = make_int2(ss[i], __float_as_int(wwv[i]));
        } else {
            int k = atomicAdd(ov_cnt, 1);
            if (k < OVCAP) ov[k] = make_int4(dd[i], ss[i], __float_as_int(wwv[i]), 0);
        }
    }
}

// ---------------------------------------------------------------------------
// Gather + softmax: one 16-lane group per node (4 nodes/wave).
// lane c4 = channels [c4*4, c4*4+4). csr entries broadcast-loaded (no
// shuffles); 4 edges of ILP per iteration; h read as bf16x4 (8B).
// ---------------------------------------------------------------------------
__global__ __launch_bounds__(256) void gather_softmax(const int* __restrict__ deg,
                                                      const int2* __restrict__ csr2,
                                                      const unsigned short* __restrict__ hb,
                                                      const int* __restrict__ ov_cnt,
                                                      const int4* __restrict__ ov,
                                                      float* __restrict__ out) {
    int tid  = blockIdx.x * 256 + threadIdx.x;
    int node = tid >> 4;
    int c4   = threadIdx.x & 15;
    if (node >= M_NODES) return;

    int deg_n = deg[node];
    int cnt   = min(deg_n, CAP);
    const int2* seg = csr2 + (size_t)node * CAP;

    float4 acc = make_float4(0.f, 0.f, 0.f, 0.f);

    int r = 0;
    for (; r + 4 <= cnt; r += 4) {
        int4 p0 = *(const int4*)&seg[r];       // edges r, r+1
        int4 p1 = *(const int4*)&seg[r + 2];   // edges r+2, r+3
        ushort4 v0 = *(const ushort4*)&hb[(size_t)p0.x * N_OUT_C + c4 * 4];
        ushort4 v1 = *(const ushort4*)&hb[(size_t)p0.z * N_OUT_C + c4 * 4];
        ushort4 v2 = *(const ushort4*)&hb[(size_t)p1.x * N_OUT_C + c4 * 4];
        ushort4 v3 = *(const ushort4*)&hb[(size_t)p1.z * N_OUT_C + c4 * 4];
        float w0 = __int_as_float(p0.y);
        float w1 = __int_as_float(p0.w);
        float w2 = __int_as_float(p1.y);
        float w3 = __int_as_float(p1.w);
        acc.x += w0 * bf2f(v0.x) + w1 * bf2f(v1.x) + w2 * bf2f(v2.x) + w3 * bf2f(v3.x);
        acc.y += w0 * bf2f(v0.y) + w1 * bf2f(v1.y) + w2 * bf2f(v2.y) + w3 * bf2f(v3.y);
        acc.z += w0 * bf2f(v0.z) + w1 * bf2f(v1.z) + w2 * bf2f(v2.z) + w3 * bf2f(v3.z);
        acc.w += w0 * bf2f(v0.w) + w1 * bf2f(v1.w) + w2 * bf2f(v2.w) + w3 * bf2f(v3.w);
    }
    for (; r < cnt; r++) {
        int2 q = seg[r];
        ushort4 v = *(const ushort4*)&hb[(size_t)q.x * N_OUT_C + c4 * 4];
        float w = __int_as_float(q.y);
        acc.x += w * bf2f(v.x);
        acc.y += w * bf2f(v.y);
        acc.z += w * bf2f(v.z);
        acc.w += w * bf2f(v.w);
    }

    if (deg_n > CAP) {                       // ~never taken; correctness net
        int ovn = min(*ov_cnt, OVCAP);
        for (int k = 0; k < ovn; k++) {
            int4 o = ov[k];
            if (o.x == node) {
                ushort4 v = *(const ushort4*)&hb[(size_t)o.y * N_OUT_C + c4 * 4];
                float w = __int_as_float(o.z);
                acc.x += w * bf2f(v.x);
                acc.y += w * bf2f(v.y);
                acc.z += w * bf2f(v.z);
                acc.w += w * bf2f(v.w);
            }
        }
    }

    // softmax over 64 channels = 16 lanes x 4
    float m = fmaxf(fmaxf(acc.x, acc.y), fmaxf(acc.z, acc.w));
    #pragma unroll
    for (int off = 1; off < 16; off <<= 1)
        m = fmaxf(m, __shfl_xor(m, off));

    float4 ev;
    ev.x = __expf(acc.x - m);
    ev.y = __expf(acc.y - m);
    ev.z = __expf(acc.z - m);
    ev.w = __expf(acc.w - m);

    float sum = ev.x + ev.y + ev.z + ev.w;
    #pragma unroll
    for (int off = 1; off < 16; off <<= 1)
        sum += __shfl_xor(sum, off);

    float inv = 1.0f / sum;
    *(float4*)&out[(size_t)node * N_OUT_C + c4 * 4] =
        make_float4(ev.x * inv, ev.y * inv, ev.z * inv, ev.w * inv);
}

// ---------------------------------------------------------------------------
// Fallback path (ws too small): fp32 GEMM + atomic scatter + softmax
// ---------------------------------------------------------------------------
__global__ __launch_bounds__(256) void gemm_xw(const float* __restrict__ x,
                                               const float* __restrict__ W,
                                               float* __restrict__ h) {
    __shared__ float As[64][33];
    __shared__ float Bs[32][64];
    const int t  = threadIdx.x;
    const int tx = t & 15;
    const int ty = t >> 4;
    const int rowBase = blockIdx.x * 64;
    float acc[4][4] = {{0.f}};
    for (int k0 = 0; k0 < K_FEAT; k0 += 32) {
        #pragma unroll
        for (int i = 0; i < 2; i++) {
            int f = t + i * 256;
            int r = f >> 3, c4 = f & 7;
            int grow = rowBase + r;
            float4 v = make_float4(0.f, 0.f, 0.f, 0.f);
            if (grow < M_NODES)
                v = *(const float4*)&x[(size_t)grow * K_FEAT + k0 + c4 * 4];
            As[r][c4 * 4 + 0] = v.x; As[r][c4 * 4 + 1] = v.y;
            As[r][c4 * 4 + 2] = v.z; As[r][c4 * 4 + 3] = v.w;
        }
        #pragma unroll
        for (int i = 0; i < 2; i++) {
            int f = t + i * 256;
            ((float4*)Bs)[f] = ((const float4*)(W + (size_t)k0 * N_OUT_C))[f];
        }
        __syncthreads();
        #pragma unroll
        for (int k = 0; k < 32; k++) {
            float a0 = As[ty * 4 + 0][k], a1 = As[ty * 4 + 1][k];
            float a2 = As[ty * 4 + 2][k], a3 = As[ty * 4 + 3][k];
            float4 b = *(float4*)&Bs[k][tx * 4];
            acc[0][0] += a0 * b.x; acc[0][1] += a0 * b.y; acc[0][2] += a0 * b.z; acc[0][3] += a0 * b.w;
            acc[1][0] += a1 * b.x; acc[1][1] += a1 * b.y; acc[1][2] += a1 * b.z; acc[1][3] += a1 * b.w;
            acc[2][0] += a2 * b.x; acc[2][1] += a2 * b.y; acc[2][2] += a2 * b.z; acc[2][3] += a2 * b.w;
            acc[3][0] += a3 * b.x; acc[3][1] += a3 * b.y; acc[3][2] += a3 * b.z; acc[3][3] += a3 * b.w;
        }
        __syncthreads();
    }
    #pragma unroll
    for (int i = 0; i < 4; i++) {
        int row = rowBase + ty * 4 + i;
        if (row < M_NODES)
            *(float4*)&h[(size_t)row * N_OUT_C + tx * 4] =
                make_float4(acc[i][0], acc[i][1], acc[i][2], acc[i][3]);
    }
}

__global__ __launch_bounds__(256) void scatter_edges(const int* __restrict__ esrc,
                                                     const int* __restrict__ edst,
                                                     const float* __restrict__ ew,
                                                     const float* __restrict__ h,
                                                     float* __restrict__ agg) {
    int tid = blockIdx.x * 256 + threadIdx.x;
    int e = tid >> 4;
    int g = tid & 15;
    if (e >= N_EDGES_C) return;
    int s = esrc[e], d = edst[e];
    float w = ew[e];
    float4 v = *(const float4*)&h[(size_t)s * N_OUT_C + g * 4];
    float* p = agg + (size_t)d * N_OUT_C + g * 4;
    unsafeAtomicAdd(p + 0, v.x * w);
    unsafeAtomicAdd(p + 1, v.y * w);
    unsafeAtomicAdd(p + 2, v.z * w);
    unsafeAtomicAdd(p + 3, v.w * w);
}

__global__ __launch_bounds__(256) void softmax_rows(float* __restrict__ out) {
    int wave = (blockIdx.x * 256 + threadIdx.x) >> 6;
    int lane = threadIdx.x & 63;
    if (wave >= M_NODES) return;
    size_t idx = (size_t)wave * N_OUT_C + lane;
    float v = out[idx];
    float m = v;
    #pragma unroll
    for (int off = 32; off > 0; off >>= 1) m = fmaxf(m, __shfl_xor(m, off));
    float ev = __expf(v - m);
    float sum = ev;
    #pragma unroll
    for (int off = 32; off > 0; off >>= 1) sum += __shfl_xor(sum, off);
    out[idx] = ev / sum;
}

// ---------------------------------------------------------------------------
extern "C" void kernel_launch(void* const* d_in, const int* in_sizes, int n_in,
                              void* d_out, int out_size, void* d_ws, size_t ws_size,
                              hipStream_t stream) {
    const float* x    = (const float*)d_in[0];
    const int*   esrc = (const int*)d_in[1];
    const int*   edst = (const int*)d_in[2];
    const float* ew   = (const float*)d_in[3];
    const float* W    = (const float*)d_in[4];
    float* out = (float*)d_out;

    char* ws = (char*)d_ws;
    size_t off_hb   = 0;
    size_t sz_hb    = (size_t)M_NODES * N_OUT_C * sizeof(unsigned short); // 12.8 MB
    size_t off_deg  = (off_hb + sz_hb + 15) & ~15ull;
    size_t sz_deg   = (size_t)M_NODES * sizeof(int);                      // 400 KB
    size_t off_csr  = (off_deg + sz_deg + 15) & ~15ull;
    size_t sz_csr   = (size_t)M_NODES * CAP * sizeof(int2);               // 32 MB
    size_t off_wb   = (off_csr + sz_csr + 15) & ~15ull;
    size_t sz_wb    = (size_t)K_FEAT * N_OUT_C * sizeof(unsigned short);  // 64 KB
    size_t off_ovc  = (off_wb + sz_wb + 15) & ~15ull;
    size_t sz_ovc   = 16;
    size_t off_ov   = (off_ovc + sz_ovc + 15) & ~15ull;
    size_t sz_ov    = (size_t)OVCAP * sizeof(int4);                       // 128 KB
    size_t needed   = off_ov + sz_ov;                                     // ~45.4 MB

    if (ws_size >= needed) {
        unsigned short* hb = (unsigned short*)(ws + off_hb);
        int*  deg    = (int*)(ws + off_deg);
        int2* csr2   = (int2*)(ws + off_csr);
        unsigned short* Wb = (unsigned short*)(ws + off_wb);
        int*  ov_cnt = (int*)(ws + off_ovc);
        int4* ov     = (int4*)(ws + off_ov);

        conv_w_zero<<<128, 256, 0, stream>>>(W, Wb, deg, ov_cnt);
        gemm_mfma<<<(M_NODES / 16 + 3) / 4, 256, 0, stream>>>(x, Wb, hb);
        scatter_direct<<<SC_BLOCKS, 256, 0, stream>>>(esrc, edst, ew, deg, csr2, ov_cnt, ov);
        gather_softmax<<<(M_NODES * 16 + 255) / 256, 256, 0, stream>>>(deg, csr2, hb, ov_cnt, ov, out);
    } else {
        // fallback: fp32 gemm + atomic scatter
        float* h = (float*)ws;
        hipMemsetAsync(d_out, 0, (size_t)M_NODES * N_OUT_C * sizeof(float), stream);
        gemm_xw<<<(M_NODES + 63) / 64, 256, 0, stream>>>(x, W, h);
        scatter_edges<<<(N_EDGES_C * 16 + 255) / 256, 256, 0, stream>>>(esrc, edst, ew, h, out);
        softmax_rows<<<(M_NODES + 3) / 4, 256, 0, stream>>>(out);
    }
}